// Round 3
// baseline (2238.011 us; speedup 1.0000x reference)
//
#include <hip/hip_runtime.h>

// Problem: B=4, S=2048, D=2048, H=16, hs=128.
// Inputs/outputs fp32 (per reference); internal compute bf16 MFMA
// (harness threshold is relaxed to the bf16 floor: floor_eps_k=8).
// d_out (fp32): [0, 16777216) ff_o [B,S,D]; [16777216, 50331648) kv [2,B,H,S,hs]
// d_ws  (bf16): [0, 16777216) q [64(bh),2048,128] -> overwritten in-place by attn_o

using floatx4 = __attribute__((ext_vector_type(4))) float;
using short8  = __attribute__((ext_vector_type(8))) short;

#define MFMA_BF16(a, b, c) __builtin_amdgcn_mfma_f32_16x16x32_bf16((a), (b), (c), 0, 0, 0)

static __device__ __forceinline__ unsigned short f2bf(float f) {
    unsigned u = __float_as_uint(f);
    u += 0x7FFF + ((u >> 16) & 1);   // round-to-nearest-even
    return (unsigned short)(u >> 16);
}
// load 8 consecutive floats, convert to 8 bf16
static __device__ __forceinline__ short8 cvt8(const float* p) {
    float4 a = ((const float4*)p)[0];
    float4 b = ((const float4*)p)[1];
    short8 r;
    r[0] = (short)f2bf(a.x); r[1] = (short)f2bf(a.y);
    r[2] = (short)f2bf(a.z); r[3] = (short)f2bf(a.w);
    r[4] = (short)f2bf(b.x); r[5] = (short)f2bf(b.y);
    r[6] = (short)f2bf(b.z); r[7] = (short)f2bf(b.w);
    return r;
}

// ---------------------------------------------------------------------------
// GEMM1: x[8192,2048] @ w_proj[6144,2048]^T + b_proj -> q(bf16 ws), k/v(fp32 out)
// ---------------------------------------------------------------------------
__global__ __launch_bounds__(256) void gemm_qkv_kernel(
    const float* __restrict__ X,     // [8192, 2048]
    const float* __restrict__ W,     // [6144, 2048]
    const float* __restrict__ Bias,  // [6144]
    unsigned short* __restrict__ Qws,// [64, 2048, 128] bf16
    float* __restrict__ KV)          // [2, 64, 2048, 128] fp32
{
    const int K = 2048;
    __shared__ short As[64][72];   // +8 pad: 144B rows, 16B-aligned frags
    __shared__ short Bs[64][72];
    const int n0 = blockIdx.x * 64;
    const int m0 = blockIdx.y * 64;
    const int t = threadIdx.x;
    const int wv = t >> 6;
    const int l = t & 63;
    const int lr = l & 15;
    const int lq = l >> 4;
    const int srow = t >> 2;
    const int scol = (t & 3) << 4;

    floatx4 acc[4] = {{0,0,0,0},{0,0,0,0},{0,0,0,0},{0,0,0,0}};

    const float* gA = X + (size_t)(m0 + srow) * K + scol;
    const float* gB = W + (size_t)(n0 + srow) * K + scol;

    for (int k0 = 0; k0 < K; k0 += 64) {
        short8 a0 = cvt8(gA + k0);
        short8 a1 = cvt8(gA + k0 + 8);
        short8 b0 = cvt8(gB + k0);
        short8 b1 = cvt8(gB + k0 + 8);
        __syncthreads();
        *(short8*)&As[srow][scol]     = a0;
        *(short8*)&As[srow][scol + 8] = a1;
        *(short8*)&Bs[srow][scol]     = b0;
        *(short8*)&Bs[srow][scol + 8] = b1;
        __syncthreads();
#pragma unroll
        for (int kc = 0; kc < 2; ++kc) {
            short8 a = *(const short8*)&As[wv * 16 + lr][kc * 32 + lq * 8];
#pragma unroll
            for (int j = 0; j < 4; ++j) {
                short8 b = *(const short8*)&Bs[j * 16 + lr][kc * 32 + lq * 8];
                acc[j] = MFMA_BF16(a, b, acc[j]);
            }
        }
    }
    // epilogue: C row = m0 + wv*16 + lq*4 + r, col = n0 + j*16 + lr  (m89 layout)
#pragma unroll
    for (int j = 0; j < 4; ++j) {
        int e = n0 + j * 16 + lr;
        int h = e / 384;
        int c = e - h * 384;          // within head: q[0,128) k[128,256) v[256,384)
        float bias = Bias[e];
#pragma unroll
        for (int r = 0; r < 4; ++r) {
            int m = m0 + wv * 16 + lq * 4 + r;
            int b = m >> 11, s = m & 2047;
            float o = acc[j][r] + bias;
            size_t base = (((size_t)(b * 16 + h)) * 2048 + s) * 128;
            if (c < 128)      Qws[base + c] = f2bf(o);
            else if (c < 256) KV[base + (c - 128)] = o;
            else              KV[(size_t)16777216 + base + (c - 256)] = o;
        }
    }
}

// ---------------------------------------------------------------------------
// Flash attention: one block per (head, 32-row q tile); 32-key kv tiles, MFMA.
// Q bf16 from ws (overwritten in-place by O); K/V fp32 from d_out kv region.
// ---------------------------------------------------------------------------
__global__ __launch_bounds__(256) void attn_kernel(
    unsigned short* __restrict__ QA,   // [64, 2048, 128] bf16: q in, attn_o out
    const float* __restrict__ KV)      // [2, 64, 2048, 128] fp32
{
    const int S = 2048;
    __shared__ short Qs[32][136];
    __shared__ short Ks[32][136];
    __shared__ short Vt[128][40];      // transposed: [d][key]
    __shared__ float Stile[32][33];
    __shared__ short Pb[32][40];       // P in bf16, A-layout source
    __shared__ float arow[32];
    __shared__ float lrow_s[32];

    const int bh = blockIdx.y;         // b*16 + h
    const int q0 = blockIdx.x * 32;
    const int t = threadIdx.x;
    const int wv = t >> 6;
    const int l = t & 63;
    const int lr = l & 15;
    const int lq = l >> 4;

    unsigned short* Qp = QA + ((size_t)bh * S + q0) * 128;
    const float* Kp = KV + (size_t)bh * S * 128;
    const float* Vp = KV + (size_t)(64 + bh) * S * 128;

    {   // stage Q once: thread t -> row t>>3, cols (t&7)*16 .. +15 (bf16 uint4 x2)
        int r = t >> 3, c = (t & 7) << 4;
        uint4 v0 = *(const uint4*)(Qp + (size_t)r * 128 + c);
        uint4 v1 = *(const uint4*)(Qp + (size_t)r * 128 + c + 8);
        *(uint4*)&Qs[r][c]     = v0;
        *(uint4*)&Qs[r][c + 8] = v1;
    }

    float m_i = -1e30f, l_i = 0.0f;    // live in lanes t<32
    floatx4 oacc[2][2];
#pragma unroll
    for (int a = 0; a < 2; ++a)
#pragma unroll
        for (int b = 0; b < 2; ++b) oacc[a][b] = (floatx4){0,0,0,0};

    const int ntiles = blockIdx.x + 1; // causal: kv0 <= q0
    for (int it = 0; it < ntiles; ++it) {
        const int kv0 = it * 32;
        const int r = t >> 3, c = (t & 7) << 4;
        const float* kr = Kp + (size_t)(kv0 + r) * 128 + c;
        const float* vr = Vp + (size_t)(kv0 + r) * 128 + c;
        short8 k0s = cvt8(kr);
        short8 k1s = cvt8(kr + 8);
        short8 v0s = cvt8(vr);
        short8 v1s = cvt8(vr + 8);
        __syncthreads();               // prev phase C done with Ks/Vt
        *(short8*)&Ks[r][c]     = k0s;
        *(short8*)&Ks[r][c + 8] = k1s;
        {   // transpose V into Vt[d][key]
            union { short8 s8[2]; short s[16]; } vu;
            vu.s8[0] = v0s; vu.s8[1] = v1s;
#pragma unroll
            for (int dd = 0; dd < 16; ++dd) Vt[c + dd][r] = vu.s[dd];
        }
        __syncthreads();

        // phase A: S = Q K^T * scale (+ causal mask). Wave -> 16x16 tile.
        {
            const int i0 = (wv >> 1) * 16, j0 = (wv & 1) * 16;
            floatx4 sacc = {0,0,0,0};
#pragma unroll
            for (int kc = 0; kc < 4; ++kc) {
                short8 a = *(const short8*)&Qs[i0 + lr][kc * 32 + lq * 8];
                short8 b = *(const short8*)&Ks[j0 + lr][kc * 32 + lq * 8];
                sacc = MFMA_BF16(a, b, sacc);
            }
#pragma unroll
            for (int rr = 0; rr < 4; ++rr) {
                int irow = i0 + lq * 4 + rr;
                int jcol = j0 + lr;
                float sv = sacc[rr] * 0.08838834764831845f;  // 1/sqrt(128)
                if (kv0 + jcol > q0 + irow) sv = -1e30f;     // causal (exp -> 0)
                Stile[irow][jcol] = sv;
            }
        }
        __syncthreads();

        // phase B: online softmax, one lane per row (lanes 0..31 of wave 0)
        if (t < 32) {
            float mx = m_i;
#pragma unroll 8
            for (int j = 0; j < 32; ++j) mx = fmaxf(mx, Stile[t][j]);
            float al = __expf(m_i - mx);
            float sum = 0.0f;
#pragma unroll 4
            for (int j = 0; j < 32; j += 2) {
                float p0 = __expf(Stile[t][j] - mx);
                float p1 = __expf(Stile[t][j + 1] - mx);
                sum += p0 + p1;
                *(unsigned*)&Pb[t][j] =
                    (unsigned)f2bf(p0) | ((unsigned)f2bf(p1) << 16);
            }
            m_i = mx;
            l_i = l_i * al + sum;
            arow[t] = al;
        }
        __syncthreads();

        // phase C: O = O*alpha + P V. Wave -> 32 d-cols (2 n-tiles) x both i-halves.
        {
            short8 pa0 = *(const short8*)&Pb[lr][lq * 8];
            short8 pa1 = *(const short8*)&Pb[16 + lr][lq * 8];
            short8 vb0 = *(const short8*)&Vt[wv * 32 + lr][lq * 8];
            short8 vb1 = *(const short8*)&Vt[wv * 32 + 16 + lr][lq * 8];
            float a0[4], a1[4];
#pragma unroll
            for (int rr = 0; rr < 4; ++rr) {
                a0[rr] = arow[lq * 4 + rr];
                a1[rr] = arow[16 + lq * 4 + rr];
            }
#pragma unroll
            for (int rr = 0; rr < 4; ++rr) {
                oacc[0][0][rr] *= a0[rr];
                oacc[0][1][rr] *= a0[rr];
                oacc[1][0][rr] *= a1[rr];
                oacc[1][1][rr] *= a1[rr];
            }
            oacc[0][0] = MFMA_BF16(pa0, vb0, oacc[0][0]);
            oacc[0][1] = MFMA_BF16(pa0, vb1, oacc[0][1]);
            oacc[1][0] = MFMA_BF16(pa1, vb0, oacc[1][0]);
            oacc[1][1] = MFMA_BF16(pa1, vb1, oacc[1][1]);
        }
    }

    if (t < 32) lrow_s[t] = l_i;
    __syncthreads();

    // epilogue: O / l written back over this block's own Q rows (bf16, [bh][s][d])
#pragma unroll
    for (int ih = 0; ih < 2; ++ih) {
#pragma unroll
        for (int rr = 0; rr < 4; ++rr) {
            int i = ih * 16 + lq * 4 + rr;
            float linv = 1.0f / lrow_s[i];
#pragma unroll
            for (int nt = 0; nt < 2; ++nt) {
                int d = wv * 32 + nt * 16 + lr;
                Qp[(size_t)i * 128 + d] = f2bf(oacc[ih][nt][rr] * linv);
            }
        }
    }
}

// ---------------------------------------------------------------------------
// GEMM2: attn_o(bf16 head-major ws) @ w_ff[2048,2048]^T + b_ff -> ff_o (fp32)
// A[m=(b,s)][k=h*128+d] = AOhm[(b*16+h)][s][d]
// ---------------------------------------------------------------------------
__global__ __launch_bounds__(256) void gemm_ff_kernel(
    const unsigned short* __restrict__ AOhm,  // [64, 2048, 128] bf16
    const float* __restrict__ W,              // [2048, 2048]
    const float* __restrict__ Bias,           // [2048]
    float* __restrict__ Out)                  // [8192, 2048]
{
    const int K = 2048;
    __shared__ short As[64][72];
    __shared__ short Bs[64][72];
    const int n0 = blockIdx.x * 64;
    const int m0 = blockIdx.y * 64;
    const int t = threadIdx.x;
    const int wv = t >> 6;
    const int l = t & 63;
    const int lr = l & 15;
    const int lq = l >> 4;
    const int srow = t >> 2;
    const int scol = (t & 3) << 4;

    floatx4 acc[4] = {{0,0,0,0},{0,0,0,0},{0,0,0,0},{0,0,0,0}};

    const int mrow = m0 + srow;
    const int b = mrow >> 11, s = mrow & 2047;
    const unsigned short* gA = AOhm + (size_t)(b * 16) * 262144 + (size_t)s * 128;
    const float* gB = W + (size_t)(n0 + srow) * K + scol;

    for (int k0 = 0; k0 < K; k0 += 64) {
        int kk = k0 + scol;            // 16-aligned; 16|128 so chunk is in one head
        int h = kk >> 7, d = kk & 127;
        const unsigned short* pa = gA + (size_t)h * 262144 + d;
        uint4 av0 = *(const uint4*)(pa);
        uint4 av1 = *(const uint4*)(pa + 8);
        short8 b0 = cvt8(gB + k0);
        short8 b1 = cvt8(gB + k0 + 8);
        __syncthreads();
        *(uint4*)&As[srow][scol]      = av0;
        *(uint4*)&As[srow][scol + 8]  = av1;
        *(short8*)&Bs[srow][scol]     = b0;
        *(short8*)&Bs[srow][scol + 8] = b1;
        __syncthreads();
#pragma unroll
        for (int kc = 0; kc < 2; ++kc) {
            short8 a = *(const short8*)&As[wv * 16 + lr][kc * 32 + lq * 8];
#pragma unroll
            for (int j = 0; j < 4; ++j) {
                short8 b2 = *(const short8*)&Bs[j * 16 + lr][kc * 32 + lq * 8];
                acc[j] = MFMA_BF16(a, b2, acc[j]);
            }
        }
    }
#pragma unroll
    for (int j = 0; j < 4; ++j) {
        int e = n0 + j * 16 + lr;
        float bias = Bias[e];
#pragma unroll
        for (int r = 0; r < 4; ++r) {
            int m = m0 + wv * 16 + lq * 4 + r;
            Out[(size_t)m * 2048 + e] = acc[j][r] + bias;
        }
    }
}

extern "C" void kernel_launch(void* const* d_in, const int* in_sizes, int n_in,
                              void* d_out, int out_size, void* d_ws, size_t ws_size,
                              hipStream_t stream) {
    const float* X  = (const float*)d_in[0];  // x
    const float* Wp = (const float*)d_in[1];  // w_proj
    const float* bp = (const float*)d_in[2];  // b_proj
    const float* Wf = (const float*)d_in[3];  // w_ff
    const float* bf = (const float*)d_in[4];  // b_ff

    float* out = (float*)d_out;
    float* kv  = out + 16777216;              // next_prefix_kv [2,4,16,2048,128] fp32
    unsigned short* Qws = (unsigned short*)d_ws; // q -> attn_o in-place, bf16, 32 MiB

    gemm_qkv_kernel<<<dim3(96, 128), 256, 0, stream>>>(X, Wp, bp, Qws, kv);
    attn_kernel<<<dim3(64, 64), 256, 0, stream>>>(Qws, kv);
    gemm_ff_kernel<<<dim3(32, 128), 256, 0, stream>>>(Qws, Wf, bf, out);
}